// Round 2
// baseline (1258.785 us; speedup 1.0000x reference)
//
#include <hip/hip_runtime.h>

// VQ-VAE quantization: N=32768, K=4096, D=256, fp32.
// Outputs (concat float32): z_q [N*D], idx [N] (as float), one_hot [N*K].
//
// Exact 3-way bf16 split (x=xh+xm+xl, exact for fp32's 24-bit mantissa);
// 6 MFMA products (hh,hm,mh,mm,hl,lh); rank by (||e||^2 - 2 z.e).
//
// Round-8 (resubmit; round-1 bench died on container acquire, not the kernel).
// Kill the VALU address tax and LDS re-read tax. Loop restructured as
// ktp(runtime) -> dc(compile-time unrolled) -> g in {0,1} (kt = 2*ktp+g):
//  - dc/rt/c compile-time => ds_read_b128 A-frag addresses become immediate
//    offsets, escr addresses strength-reduce to one base per ktp.
//  - A fragments for a dc are loaded once into 48 VGPRs and reused by both kt
//    of the pair => LDS read count halves.
//  - B ping-pong parity is the compile-time g bit; accumulation order per acc
//    is unchanged => distances (and therefore idx/one_hot) are bit-identical.

#define N_TOK 32768
#define K_CODE 4096
#define D_DIM 256
#define BM 64

typedef float f32x4 __attribute__((ext_vector_type(4)));
typedef short s16x8 __attribute__((ext_vector_type(8)));

// d_out tail scratch: e_frags ushort[3*K*D] = 6,291,456 B, then e2 float[K]
#define OUT_FLOATS 142639104u          // N*D + N + N*K
#define SCR_FLOATS 1576960u            // 3*K*D/2 + K
#define SCR_OFF    (OUT_FLOATS - SCR_FLOATS)
#define EFRAG_SHORTS (3u * K_CODE * D_DIM)
#define OH_SAFE_ROWS 32320             // rows >= this: one_hot overlaps scratch region

#define MFMA(a, b, c) __builtin_amdgcn_mfma_f32_16x16x32_bf16((a), (b), (c), 0, 0, 0)

static __device__ __forceinline__ unsigned short f2bf(float f) {
    unsigned int u = __float_as_uint(f);
    u = (u + 0x7fffu + ((u >> 16) & 1u)) >> 16;
    return (unsigned short)u;
}
static __device__ __forceinline__ float bf2f(unsigned short b) {
    return __uint_as_float(((unsigned int)b) << 16);
}

// ---------------------------------------------------------------------------
// Prep: embed -> fragment-ordered bf16 h/m/l planes + e2.
// Frag layout (1KB): [ct_g(256)][dc(8)][c(3)][lane(64)][8 bf16];
// e[k][d]: ct_g=k>>4, n=k&15, dc=d>>5, quad=(d>>3)&3, j=d&7, lane=quad*16+n.
// ---------------------------------------------------------------------------
__global__ __launch_bounds__(256) void vq_prep(const float* __restrict__ embed,
                                               float* __restrict__ out) {
    __shared__ float part[8][33];
    unsigned short* escr = (unsigned short*)(out + SCR_OFF);
    float* e2g = out + SCR_OFF + (EFRAG_SHORTS / 2);

    const int t    = threadIdx.x;
    const int cl   = t >> 5;
    const int r32  = t & 31;
    const int dc   = r32 >> 2;
    const int quad = r32 & 3;
    const int k    = blockIdx.x * 8 + cl;

    const float* src = embed + (size_t)k * D_DIM + dc * 32 + quad * 8;
    float x[8];
    *(float4*)(x)     = *(const float4*)(src);
    *(float4*)(x + 4) = *(const float4*)(src + 4);

    s16x8 hv, mv, lv;
    float s2 = 0.0f;
#pragma unroll
    for (int j = 0; j < 8; ++j) {
        const float xx = x[j];
        s2 += xx * xx;
        const unsigned short bh = f2bf(xx);
        const float r1 = xx - bf2f(bh);
        const unsigned short bm = f2bf(r1);
        hv[j] = (short)bh; mv[j] = (short)bm; lv[j] = (short)f2bf(r1 - bf2f(bm));
    }

    const int ct_g = k >> 4;
    const int lane = quad * 16 + (k & 15);
    const size_t base = ((size_t)(ct_g * 8 + dc) * 3) * 512 + lane * 8;
    *(s16x8*)&escr[base]        = hv;
    *(s16x8*)&escr[base + 512]  = mv;
    *(s16x8*)&escr[base + 1024] = lv;

    part[cl][r32] = s2;
    __syncthreads();
    if (t < 8) {
        float s = 0.0f;
#pragma unroll
        for (int j = 0; j < 32; ++j) s += part[t][j];   // fixed order: deterministic
        e2g[blockIdx.x * 8 + t] = s;
    }
}

// ---------------------------------------------------------------------------
// Argmin + fused outputs: 512 thr = 8 waves, 64 rows/block, grid 512 (1 block/CU,
// 2 rounds). LDS = A only (96KB). Loop: ktp(8, runtime) x dc(8, unrolled) x
// g(2): A-frags in regs per dc reused across the kt pair; B register ping-pong
// with compile-time parity. Tail: idx + nontemporal z_q + one_hot (skipped for
// rows >= 32320).
// ---------------------------------------------------------------------------
__global__ __launch_bounds__(512, 2)
void vq_argmin_mfma(const float* __restrict__ z_e,
                    const float* __restrict__ embed,
                    float* __restrict__ out) {
    __shared__ __align__(16) short As[49152];   // [(c*4+rtile)*8+dc]*512 + ls*8
    __shared__ float redv[64][9];
    __shared__ int   redi[64][9];
    __shared__ int   bk_lds[64];

    const unsigned short* escr = (const unsigned short*)(out + SCR_OFF);
    const float* e2g = out + SCR_OFF + (EFRAG_SHORTS / 2);

    const int t    = threadIdx.x;
    const int w    = t >> 6;
    const int lane = t & 63;
    const int n    = lane & 15;
    const int quad = lane >> 4;
    const int row0 = blockIdx.x * BM;

    // ---- stage + convert A (once) ----
#pragma unroll
    for (int i = 0; i < 4; ++i) {
        const int run  = t + 512 * i;           // (row, dcs, qs): 64*8*4 = 2048
        const int qs   = run & 3;
        const int dcs  = (run >> 2) & 7;
        const int row  = run >> 5;
        const float* src = z_e + (size_t)(row0 + row) * D_DIM + dcs * 32 + qs * 8;
        float x[8];
        *(float4*)(x)     = *(const float4*)(src);
        *(float4*)(x + 4) = *(const float4*)(src + 4);
        s16x8 hv, mv, lv;
#pragma unroll
        for (int j = 0; j < 8; ++j) {
            const float xx = x[j];
            const unsigned short bh = f2bf(xx);
            const float r1 = xx - bf2f(bh);
            const unsigned short bm = f2bf(r1);
            hv[j] = (short)bh; mv[j] = (short)bm; lv[j] = (short)f2bf(r1 - bf2f(bm));
        }
        const int rtile = row >> 4;
        const int ls    = qs * 16 + (row & 15);
        *(s16x8*)&As[((0 * 4 + rtile) * 8 + dcs) * 512 + ls * 8] = hv;
        *(s16x8*)&As[((1 * 4 + rtile) * 8 + dcs) * 512 + ls * 8] = mv;
        *(s16x8*)&As[((2 * 4 + rtile) * 8 + dcs) * 512 + ls * 8] = lv;
    }
    __syncthreads();

    float bv[16];
    int   bidx[16];
#pragma unroll
    for (int s = 0; s < 16; ++s) { bv[s] = 3.0e38f; bidx[s] = 0; }

    f32x4 acc[2][4][2];                          // [g][rt][u]
#pragma unroll
    for (int g = 0; g < 2; ++g)
#pragma unroll
        for (int rt = 0; rt < 4; ++rt)
#pragma unroll
            for (int u = 0; u < 2; ++u) acc[g][rt][u] = (f32x4){0.f, 0.f, 0.f, 0.f};

    float e2r[2][2];
    s16x8 Bb[2][2][3];                           // [parity(=g)][u][c]

    // escr offset (shorts) for (ktp,g,u,dc,c):
    //   ktp*393216 + g*196608 + u*12288 + (w*2)*12288 + dc*1536 + c*512 + lane*8
    const unsigned short* ewbase = escr + (size_t)(w * 2) * 12288 + lane * 8;

    // prologue: (ktp=0, g=0, dc=0) -> Bb[0]
#pragma unroll
    for (int u = 0; u < 2; ++u)
#pragma unroll
        for (int c = 0; c < 3; ++c)
            Bb[0][u][c] = *(const s16x8*)(ewbase + u * 12288 + c * 512);

#pragma unroll 1
    for (int ktp = 0; ktp < 8; ++ktp) {
        const unsigned short* ep  = ewbase + (size_t)ktp * 393216;
        const unsigned short* epn = ewbase + (size_t)(ktp < 7 ? ktp + 1 : 7) * 393216;

#pragma unroll
        for (int g = 0; g < 2; ++g)
#pragma unroll
            for (int u = 0; u < 2; ++u)
                e2r[g][u] = e2g[ktp * 512 + g * 256 + (w * 2 + u) * 16 + n];

#pragma unroll
        for (int dc = 0; dc < 8; ++dc) {
            // A-frags for this dc: loaded once, reused by g=0 and g=1.
            // dc/rt/c compile-time => immediate ds offsets.
            s16x8 af[4][3];
#pragma unroll
            for (int rt = 0; rt < 4; ++rt)
#pragma unroll
                for (int c = 0; c < 3; ++c)
                    af[rt][c] = *(const s16x8*)&As[((c * 4 + rt) * 8 + dc) * 512 + lane * 8];

#pragma unroll
            for (int g = 0; g < 2; ++g) {
                // prefetch next step into Bb[g^1]:
                //   g==0 -> (ktp, dc, g=1); g==1 -> dc<7 ? (ktp, dc+1, 0)
                //                                        : (ktp+1, 0, 0) [clamped]
                const unsigned short* np = (g == 0) ? (ep + 196608 + dc * 1536)
                                         : (dc < 7) ? (ep + (dc + 1) * 1536)
                                                    : epn;
#pragma unroll
                for (int u = 0; u < 2; ++u)
#pragma unroll
                    for (int c = 0; c < 3; ++c)
                        Bb[g ^ 1][u][c] = *(const s16x8*)(np + u * 12288 + c * 512);

                // same 6-product chain order as before => bit-identical acc
#pragma unroll
                for (int rt = 0; rt < 4; ++rt)
#pragma unroll
                    for (int u = 0; u < 2; ++u) {
                        f32x4 a = acc[g][rt][u];
                        a = MFMA(af[rt][0], Bb[g][u][0], a);
                        a = MFMA(af[rt][0], Bb[g][u][1], a);
                        a = MFMA(af[rt][1], Bb[g][u][0], a);
                        a = MFMA(af[rt][1], Bb[g][u][1], a);
                        a = MFMA(af[rt][0], Bb[g][u][2], a);
                        a = MFMA(af[rt][2], Bb[g][u][0], a);
                        acc[g][rt][u] = a;
                    }
            }
        }

        // merge: codes ascend over (g,u) per slot -> strict < = first occurrence
#pragma unroll
        for (int g = 0; g < 2; ++g)
#pragma unroll
            for (int u = 0; u < 2; ++u) {
                const int code = (ktp * 2 + g) * 256 + (w * 2 + u) * 16 + n;
#pragma unroll
                for (int rt = 0; rt < 4; ++rt)
#pragma unroll
                    for (int r = 0; r < 4; ++r) {
                        const float val = fmaf(-2.0f, acc[g][rt][u][r], e2r[g][u]);
                        const int slot = rt * 4 + r;
                        if (val < bv[slot]) { bv[slot] = val; bidx[slot] = code; }
                    }
            }
#pragma unroll
        for (int g = 0; g < 2; ++g)
#pragma unroll
            for (int rt = 0; rt < 4; ++rt)
#pragma unroll
                for (int u = 0; u < 2; ++u) acc[g][rt][u] = (f32x4){0.f, 0.f, 0.f, 0.f};
    }

    // butterfly over 16 lanes (codes interleave mod 16 -> lex tie-break)
#pragma unroll
    for (int slot = 0; slot < 16; ++slot) {
#pragma unroll
        for (int mask = 1; mask < 16; mask <<= 1) {
            const float ov = __shfl_xor(bv[slot], mask);
            const int   oi = __shfl_xor(bidx[slot], mask);
            if (ov < bv[slot] || (ov == bv[slot] && oi < bidx[slot])) {
                bv[slot] = ov; bidx[slot] = oi;
            }
        }
    }
    if (n == 0) {
#pragma unroll
        for (int rt = 0; rt < 4; ++rt)
#pragma unroll
            for (int r = 0; r < 4; ++r) {
                const int row_local = rt * 16 + quad * 4 + r;   // C/D: row=quad*4+reg
                redv[row_local][w] = bv[rt * 4 + r];
                redi[row_local][w] = bidx[rt * 4 + r];
            }
    }
    __syncthreads();
    if (t < 64) {
        float v = redv[t][0];
        int  bi = redi[t][0];
#pragma unroll
        for (int j = 1; j < 8; ++j) {
            const float v2 = redv[t][j];
            const int   i2 = redi[t][j];
            if (v2 < v || (v2 == v && i2 < bi)) { v = v2; bi = i2; }
        }
        bk_lds[t] = bi;
        out[(size_t)N_TOK * D_DIM + (size_t)(row0 + t)] = (float)bi;
    }
    __syncthreads();

    // ---- fused output tail (nontemporal: bypass L2, keep B scratch hot) ----
    float* zq = out;
    float* oh = out + (size_t)N_TOK * D_DIM + N_TOK;

#pragma unroll 1
    for (int rr = 0; rr < 8; ++rr) {            // z_q: wave w owns rows w*8..w*8+7
        const int rl  = w * 8 + rr;
        const int row = row0 + rl;
        const int bk  = bk_lds[rl];
        f32x4 v = *(const f32x4*)&embed[(size_t)bk * D_DIM + lane * 4];
        __builtin_nontemporal_store(v, (f32x4*)&zq[(size_t)row * D_DIM + lane * 4]);
    }
    if (row0 < OH_SAFE_ROWS) {                  // one_hot (scratch-overlap rows deferred)
#pragma unroll 1
        for (int rr = 0; rr < 8; ++rr) {
            const int rl  = w * 8 + rr;
            const int row = row0 + rl;
            const int bk  = bk_lds[rl];
            float* ohrow = &oh[(size_t)row * K_CODE];
#pragma unroll
            for (int g = 0; g < 16; ++g) {
                const int base = (g * 64 + lane) * 4;
                f32x4 u;
                u.x = (bk == base    ) ? 1.0f : 0.0f;
                u.y = (bk == base + 1) ? 1.0f : 0.0f;
                u.z = (bk == base + 2) ? 1.0f : 0.0f;
                u.w = (bk == base + 3) ? 1.0f : 0.0f;
                __builtin_nontemporal_store(u, (f32x4*)&ohrow[base]);
            }
        }
    }
}

// ---------------------------------------------------------------------------
// Cleanup: one_hot for rows 32320..32767 (region overlapped the scratch).
// 28 blocks x 16 rows; runs after all argmin blocks (stream order).
// ---------------------------------------------------------------------------
__launch_bounds__(256, 8)
__global__ void vq_oh_tail(float* __restrict__ out) {
    __shared__ int bks[16];
    const int t    = threadIdx.x;
    const int w    = t >> 6;
    const int lane = t & 63;
    const int row0 = OH_SAFE_ROWS + blockIdx.x * 16;

    const float* idxf = out + (size_t)N_TOK * D_DIM;
    float* oh = out + (size_t)N_TOK * D_DIM + N_TOK;

    if (t < 16) bks[t] = (int)idxf[row0 + t];
    __syncthreads();

#pragma unroll 1
    for (int rr = 0; rr < 4; ++rr) {
        const int r   = rr * 4 + w;
        const int row = row0 + r;
        const int bk  = bks[r];
        float* ohrow = &oh[(size_t)row * K_CODE];
#pragma unroll
        for (int g = 0; g < 16; ++g) {
            const int base = (g * 64 + lane) * 4;
            f32x4 u;
            u.x = (bk == base    ) ? 1.0f : 0.0f;
            u.y = (bk == base + 1) ? 1.0f : 0.0f;
            u.z = (bk == base + 2) ? 1.0f : 0.0f;
            u.w = (bk == base + 3) ? 1.0f : 0.0f;
            __builtin_nontemporal_store(u, (f32x4*)&ohrow[base]);
        }
    }
}

extern "C" void kernel_launch(void* const* d_in, const int* in_sizes, int n_in,
                              void* d_out, int out_size, void* d_ws, size_t ws_size,
                              hipStream_t stream) {
    const float* z_e   = (const float*)d_in[0];
    const float* embed = (const float*)d_in[1];
    float* out = (float*)d_out;

    hipLaunchKernelGGL(vq_prep,        dim3(K_CODE / 8), dim3(256), 0, stream, embed, out);
    hipLaunchKernelGGL(vq_argmin_mfma, dim3(N_TOK / BM), dim3(512), 0, stream, z_e, embed, out);
    hipLaunchKernelGGL(vq_oh_tail,     dim3((N_TOK - OH_SAFE_ROWS) / 16), dim3(256), 0, stream, out);
}

// Round 3
// 838.979 us; speedup vs baseline: 1.5004x; 1.5004x over previous
//
#include <hip/hip_runtime.h>

// VQ-VAE quantization: N=32768, K=4096, D=256, fp32.
// Outputs (concat float32): z_q [N*D], idx [N] (as float), one_hot [N*K].
//
// Exact 3-way bf16 split (x=xh+xm+xl, exact for fp32's 24-bit mantissa);
// 6 MFMA products (hh,hm,mh,mm,hl,lh); rank by (||e||^2 - 2 z.e).
//
// Round-9: round-8's wide-tile idea inside round-7's spill-safe structure.
//  - Each wave covers u=4 code sub-tiles per step (64 codes): 64 steps instead
//    of 128; per-step fixed costs (addresses, merge, idle events) amortize over
//    2x MFMA; LDS A-reads per MFMA halve.
//  - Small runtime loop body (32 iters x 2 steps, ping-pong B) like round-7 --
//    round-8's giant unrolled body caused spills (FETCH 72MB -> 1.47GB).
//  - B base hoisted to SGPR via readfirstlane(w); step offsets are scalar.
//  - Same per-(row,code) accumulation chain & ascending-code strict-< merge
//    => bit-identical results.

#define N_TOK 32768
#define K_CODE 4096
#define D_DIM 256
#define BM 64

typedef float f32x4 __attribute__((ext_vector_type(4)));
typedef short s16x8 __attribute__((ext_vector_type(8)));

// d_out tail scratch: e_frags ushort[3*K*D] = 6,291,456 B, then e2 float[K]
#define OUT_FLOATS 142639104u          // N*D + N + N*K
#define SCR_FLOATS 1576960u            // 3*K*D/2 + K
#define SCR_OFF    (OUT_FLOATS - SCR_FLOATS)
#define EFRAG_SHORTS (3u * K_CODE * D_DIM)
#define OH_SAFE_ROWS 32320             // rows >= this: one_hot overlaps scratch region

#define MFMA(a, b, c) __builtin_amdgcn_mfma_f32_16x16x32_bf16((a), (b), (c), 0, 0, 0)

static __device__ __forceinline__ unsigned short f2bf(float f) {
    unsigned int u = __float_as_uint(f);
    u = (u + 0x7fffu + ((u >> 16) & 1u)) >> 16;
    return (unsigned short)u;
}
static __device__ __forceinline__ float bf2f(unsigned short b) {
    return __uint_as_float(((unsigned int)b) << 16);
}

// ---------------------------------------------------------------------------
// Prep: embed -> fragment-ordered bf16 h/m/l planes + e2.
// Frag layout (1KB): [ct_g(256)][dc(8)][c(3)][lane(64)][8 bf16];
// e[k][d]: ct_g=k>>4, n=k&15, dc=d>>5, quad=(d>>3)&3, j=d&7, lane=quad*16+n.
// ---------------------------------------------------------------------------
__global__ __launch_bounds__(256) void vq_prep(const float* __restrict__ embed,
                                               float* __restrict__ out) {
    __shared__ float part[8][33];
    unsigned short* escr = (unsigned short*)(out + SCR_OFF);
    float* e2g = out + SCR_OFF + (EFRAG_SHORTS / 2);

    const int t    = threadIdx.x;
    const int cl   = t >> 5;
    const int r32  = t & 31;
    const int dc   = r32 >> 2;
    const int quad = r32 & 3;
    const int k    = blockIdx.x * 8 + cl;

    const float* src = embed + (size_t)k * D_DIM + dc * 32 + quad * 8;
    float x[8];
    *(float4*)(x)     = *(const float4*)(src);
    *(float4*)(x + 4) = *(const float4*)(src + 4);

    s16x8 hv, mv, lv;
    float s2 = 0.0f;
#pragma unroll
    for (int j = 0; j < 8; ++j) {
        const float xx = x[j];
        s2 += xx * xx;
        const unsigned short bh = f2bf(xx);
        const float r1 = xx - bf2f(bh);
        const unsigned short bm = f2bf(r1);
        hv[j] = (short)bh; mv[j] = (short)bm; lv[j] = (short)f2bf(r1 - bf2f(bm));
    }

    const int ct_g = k >> 4;
    const int lane = quad * 16 + (k & 15);
    const size_t base = ((size_t)(ct_g * 8 + dc) * 3) * 512 + lane * 8;
    *(s16x8*)&escr[base]        = hv;
    *(s16x8*)&escr[base + 512]  = mv;
    *(s16x8*)&escr[base + 1024] = lv;

    part[cl][r32] = s2;
    __syncthreads();
    if (t < 8) {
        float s = 0.0f;
#pragma unroll
        for (int j = 0; j < 32; ++j) s += part[t][j];   // fixed order: deterministic
        e2g[blockIdx.x * 8 + t] = s;
    }
}

// ---- helpers for the wide-tile double-buffered main loop ------------------
static __device__ __forceinline__ void load_b4(const unsigned short* __restrict__ p,
                                               s16x8 (&buf)[4][3]) {
#pragma unroll
    for (int u = 0; u < 4; ++u)
#pragma unroll
        for (int c = 0; c < 3; ++c)
            buf[u][c] = *(const s16x8*)(p + u * 12288 + c * 512);
}

static __device__ __forceinline__ size_t boff(int s) {
    return (size_t)(s >> 3) * 393216 + (size_t)(s & 7) * 1536;
}

static __device__ __forceinline__ void proc4(const short* As,
        const float* __restrict__ e2g, int s, int wu, int lane, int n,
        s16x8 (&B)[4][3], f32x4 (&acc)[4][4], float (&e2r)[4],
        float (&bv)[16], int (&bidx)[16]) {
    const int ktp = s >> 3;
    const int dc  = s & 7;
    if (dc == 0) {       // prefetch e2 8 steps ahead of its dc==7 use
#pragma unroll
        for (int u = 0; u < 4; ++u)
            e2r[u] = e2g[ktp * 512 + (wu * 4 + u) * 16 + n];
    }
#pragma unroll
    for (int rt = 0; rt < 4; ++rt) {
        s16x8 af0 = *(const s16x8*)&As[((0 * 4 + rt) * 8 + dc) * 512 + lane * 8];
        s16x8 af1 = *(const s16x8*)&As[((1 * 4 + rt) * 8 + dc) * 512 + lane * 8];
        s16x8 af2 = *(const s16x8*)&As[((2 * 4 + rt) * 8 + dc) * 512 + lane * 8];
#pragma unroll
        for (int u = 0; u < 4; ++u) {
            f32x4 a = acc[rt][u];
            a = MFMA(af0, B[u][0], a);
            a = MFMA(af0, B[u][1], a);
            a = MFMA(af1, B[u][0], a);
            a = MFMA(af1, B[u][1], a);
            a = MFMA(af0, B[u][2], a);
            a = MFMA(af2, B[u][0], a);
            acc[rt][u] = a;
        }
    }
    if (dc == 7) {   // merge: codes ascend over (ktp,u) per slot -> strict < = first occurrence
#pragma unroll
        for (int u = 0; u < 4; ++u) {
            const int code = ktp * 512 + (wu * 4 + u) * 16 + n;
#pragma unroll
            for (int rt = 0; rt < 4; ++rt)
#pragma unroll
                for (int r = 0; r < 4; ++r) {
                    const float val = fmaf(-2.0f, acc[rt][u][r], e2r[u]);
                    const int slot = rt * 4 + r;
                    if (val < bv[slot]) { bv[slot] = val; bidx[slot] = code; }
                }
        }
#pragma unroll
        for (int rt = 0; rt < 4; ++rt)
#pragma unroll
            for (int u = 0; u < 4; ++u) acc[rt][u] = (f32x4){0.f, 0.f, 0.f, 0.f};
    }
}

// ---------------------------------------------------------------------------
// Argmin + fused outputs: 512 thr = 8 waves, 64 rows/block, grid 512 (1 block/CU,
// 2 rounds). LDS = A only (96KB). 64-step (ktp,dc) loop, each wave covering 64
// codes/step; register ping-pong B prefetch. Tail: idx + nontemporal z_q +
// one_hot (skipped for rows >= 32320).
// ---------------------------------------------------------------------------
__global__ __launch_bounds__(512, 2)
void vq_argmin_mfma(const float* __restrict__ z_e,
                    const float* __restrict__ embed,
                    float* __restrict__ out) {
    __shared__ __align__(16) short As[49152];   // [(c*4+rtile)*8+dc]*512 + ls*8
    __shared__ float redv[64][9];
    __shared__ int   redi[64][9];
    __shared__ int   bk_lds[64];

    const unsigned short* escr = (const unsigned short*)(out + SCR_OFF);
    const float* e2g = out + SCR_OFF + (EFRAG_SHORTS / 2);

    const int t    = threadIdx.x;
    const int w    = t >> 6;
    const int lane = t & 63;
    const int n    = lane & 15;
    const int quad = lane >> 4;
    const int row0 = blockIdx.x * BM;

    // ---- stage + convert A (once) ----
#pragma unroll
    for (int i = 0; i < 4; ++i) {
        const int run  = t + 512 * i;           // (row, dcs, qs): 64*8*4 = 2048
        const int qs   = run & 3;
        const int dcs  = (run >> 2) & 7;
        const int row  = run >> 5;
        const float* src = z_e + (size_t)(row0 + row) * D_DIM + dcs * 32 + qs * 8;
        float x[8];
        *(float4*)(x)     = *(const float4*)(src);
        *(float4*)(x + 4) = *(const float4*)(src + 4);
        s16x8 hv, mv, lv;
#pragma unroll
        for (int j = 0; j < 8; ++j) {
            const float xx = x[j];
            const unsigned short bh = f2bf(xx);
            const float r1 = xx - bf2f(bh);
            const unsigned short bm = f2bf(r1);
            hv[j] = (short)bh; mv[j] = (short)bm; lv[j] = (short)f2bf(r1 - bf2f(bm));
        }
        const int rtile = row >> 4;
        const int ls    = qs * 16 + (row & 15);
        *(s16x8*)&As[((0 * 4 + rtile) * 8 + dcs) * 512 + ls * 8] = hv;
        *(s16x8*)&As[((1 * 4 + rtile) * 8 + dcs) * 512 + ls * 8] = mv;
        *(s16x8*)&As[((2 * 4 + rtile) * 8 + dcs) * 512 + ls * 8] = lv;
    }
    __syncthreads();

    float bv[16];
    int   bidx[16];
#pragma unroll
    for (int s = 0; s < 16; ++s) { bv[s] = 3.0e38f; bidx[s] = 0; }

    f32x4 acc[4][4];                             // [rt][u]
#pragma unroll
    for (int rt = 0; rt < 4; ++rt)
#pragma unroll
        for (int u = 0; u < 4; ++u) acc[rt][u] = (f32x4){0.f, 0.f, 0.f, 0.f};

    float e2r[4];
    s16x8 b0[4][3], b1[4][3];

    // SGPR-provable wave-uniform B base: ct = ktp*32 + wu*4 + u.
    // escr offset (shorts) = ktp*393216 + wu*49152 + u*12288 + dc*1536 + c*512 + lane*8
    const int wu = __builtin_amdgcn_readfirstlane(w);
    const unsigned short* ebase = escr + (size_t)wu * 49152 + lane * 8;

    load_b4(ebase, b0);                          // step 0

    // 64 steps = (ktp 0..7) x (dc 0..7); ping-pong prefetch distance 1.
    // b1's loads are younger than b0's -> waiting on b0 never drains b1 (vmcnt(N)).
#pragma unroll 1
    for (int it = 0; it < 32; ++it) {
        const int s0 = it * 2, s1 = s0 + 1, s2 = s1 + 1;
        load_b4(ebase + boff(s1), b1);
        proc4(As, e2g, s0, wu, lane, n, b0, acc, e2r, bv, bidx);
        if (it < 31) load_b4(ebase + boff(s2), b0);
        proc4(As, e2g, s1, wu, lane, n, b1, acc, e2r, bv, bidx);
    }

    // butterfly over 16 lanes (codes interleave mod 16 -> lex tie-break)
#pragma unroll
    for (int slot = 0; slot < 16; ++slot) {
#pragma unroll
        for (int mask = 1; mask < 16; mask <<= 1) {
            const float ov = __shfl_xor(bv[slot], mask);
            const int   oi = __shfl_xor(bidx[slot], mask);
            if (ov < bv[slot] || (ov == bv[slot] && oi < bidx[slot])) {
                bv[slot] = ov; bidx[slot] = oi;
            }
        }
    }
    if (n == 0) {
#pragma unroll
        for (int rt = 0; rt < 4; ++rt)
#pragma unroll
            for (int r = 0; r < 4; ++r) {
                const int row_local = rt * 16 + quad * 4 + r;   // C/D: row=quad*4+reg
                redv[row_local][w] = bv[rt * 4 + r];
                redi[row_local][w] = bidx[rt * 4 + r];
            }
    }
    __syncthreads();
    if (t < 64) {
        float v = redv[t][0];
        int  bi = redi[t][0];
#pragma unroll
        for (int j = 1; j < 8; ++j) {
            const float v2 = redv[t][j];
            const int   i2 = redi[t][j];
            if (v2 < v || (v2 == v && i2 < bi)) { v = v2; bi = i2; }
        }
        bk_lds[t] = bi;
        out[(size_t)N_TOK * D_DIM + (size_t)(row0 + t)] = (float)bi;
    }
    __syncthreads();

    // ---- fused output tail (nontemporal: bypass L2, keep B scratch hot) ----
    float* zq = out;
    float* oh = out + (size_t)N_TOK * D_DIM + N_TOK;

#pragma unroll 1
    for (int rr = 0; rr < 8; ++rr) {            // z_q: wave w owns rows w*8..w*8+7
        const int rl  = w * 8 + rr;
        const int row = row0 + rl;
        const int bk  = bk_lds[rl];
        f32x4 v = *(const f32x4*)&embed[(size_t)bk * D_DIM + lane * 4];
        __builtin_nontemporal_store(v, (f32x4*)&zq[(size_t)row * D_DIM + lane * 4]);
    }
    if (row0 < OH_SAFE_ROWS) {                  // one_hot (scratch-overlap rows deferred)
#pragma unroll 1
        for (int rr = 0; rr < 8; ++rr) {
            const int rl  = w * 8 + rr;
            const int row = row0 + rl;
            const int bk  = bk_lds[rl];
            float* ohrow = &oh[(size_t)row * K_CODE];
#pragma unroll
            for (int g = 0; g < 16; ++g) {
                const int base = (g * 64 + lane) * 4;
                f32x4 u;
                u.x = (bk == base    ) ? 1.0f : 0.0f;
                u.y = (bk == base + 1) ? 1.0f : 0.0f;
                u.z = (bk == base + 2) ? 1.0f : 0.0f;
                u.w = (bk == base + 3) ? 1.0f : 0.0f;
                __builtin_nontemporal_store(u, (f32x4*)&ohrow[base]);
            }
        }
    }
}

// ---------------------------------------------------------------------------
// Cleanup: one_hot for rows 32320..32767 (region overlapped the scratch).
// 28 blocks x 16 rows; runs after all argmin blocks (stream order).
// ---------------------------------------------------------------------------
__launch_bounds__(256, 8)
__global__ void vq_oh_tail(float* __restrict__ out) {
    __shared__ int bks[16];
    const int t    = threadIdx.x;
    const int w    = t >> 6;
    const int lane = t & 63;
    const int row0 = OH_SAFE_ROWS + blockIdx.x * 16;

    const float* idxf = out + (size_t)N_TOK * D_DIM;
    float* oh = out + (size_t)N_TOK * D_DIM + N_TOK;

    if (t < 16) bks[t] = (int)idxf[row0 + t];
    __syncthreads();

#pragma unroll 1
    for (int rr = 0; rr < 4; ++rr) {
        const int r   = rr * 4 + w;
        const int row = row0 + r;
        const int bk  = bks[r];
        float* ohrow = &oh[(size_t)row * K_CODE];
#pragma unroll
        for (int g = 0; g < 16; ++g) {
            const int base = (g * 64 + lane) * 4;
            f32x4 u;
            u.x = (bk == base    ) ? 1.0f : 0.0f;
            u.y = (bk == base + 1) ? 1.0f : 0.0f;
            u.z = (bk == base + 2) ? 1.0f : 0.0f;
            u.w = (bk == base + 3) ? 1.0f : 0.0f;
            __builtin_nontemporal_store(u, (f32x4*)&ohrow[base]);
        }
    }
}

extern "C" void kernel_launch(void* const* d_in, const int* in_sizes, int n_in,
                              void* d_out, int out_size, void* d_ws, size_t ws_size,
                              hipStream_t stream) {
    const float* z_e   = (const float*)d_in[0];
    const float* embed = (const float*)d_in[1];
    float* out = (float*)d_out;

    hipLaunchKernelGGL(vq_prep,        dim3(K_CODE / 8), dim3(256), 0, stream, embed, out);
    hipLaunchKernelGGL(vq_argmin_mfma, dim3(N_TOK / BM), dim3(512), 0, stream, z_e, embed, out);
    hipLaunchKernelGGL(vq_oh_tail,     dim3((N_TOK - OH_SAFE_ROWS) / 16), dim3(256), 0, stream, out);
}